// Round 9
// baseline (306.877 us; speedup 1.0000x reference)
//
#include <hip/hip_runtime.h>
#include <stdint.h>

// Problem constants (B,S,D,H fixed by the reference)
#define SEQ 1568
#define SEQV 1600   // vtb padded s-stride: 1600*2B = 25 full 128B lines
#define DIM 1024
#define NB 4
#define NH 16
#define HD 64

typedef unsigned short u16;
typedef __bf16 bf16x8 __attribute__((ext_vector_type(8)));
typedef __bf16 bf16x4 __attribute__((ext_vector_type(4)));
typedef float f32x4 __attribute__((ext_vector_type(4)));

// log2(e)/8: folded into q so QK^T scores come out in exp2 domain
#define QSCALE 0.18033688011112042f

// sP row stride (u16). MUST be >= 64 (P tile is 32 x 64); 72 = 64 + 8 pad
// breaks the power-of-2-stride conflicts. Do not shrink below 64.
#define PSTR 72

// async global->LDS, 16B per lane. LDS dest is wave-uniform base + lane*16.
__device__ __forceinline__ void load_lds16(const u16* g, u16* s) {
  __builtin_amdgcn_global_load_lds((__attribute__((address_space(1))) void*)g,
                                   (__attribute__((address_space(3))) void*)s,
                                   16, 0, 0);
}

#define WAIT_VM(N) asm volatile("s_waitcnt vmcnt(" #N ")" ::: "memory")
#define LGKM0()    asm volatile("s_waitcnt lgkmcnt(0)" ::: "memory")
#define BAR()      do { __builtin_amdgcn_s_barrier(); \
                        __builtin_amdgcn_sched_barrier(0); } while (0)

// ---------------------------------------------------------------------------
// Fused fp32 -> bf16 convert of x + all 4 weights (one launch, 4 elems/thread)
// ---------------------------------------------------------------------------
__global__ __launch_bounds__(256) void cvt_all(
    const float* __restrict__ x,  const float* __restrict__ wq,
    const float* __restrict__ wk, const float* __restrict__ wv,
    const float* __restrict__ wp,
    u16* __restrict__ xb, u16* __restrict__ wqb, u16* __restrict__ wkb,
    u16* __restrict__ wvb, u16* __restrict__ wpb) {
  int i = blockIdx.x * 256 + threadIdx.x;   // grid sized exactly: 2654208 total
  const float* src; u16* dst; int off;
  if (i < 1605632)      { src = x;  dst = xb;  off = i; }
  else if (i < 1867776) { src = wq; dst = wqb; off = i - 1605632; }
  else if (i < 2129920) { src = wk; dst = wkb; off = i - 1867776; }
  else if (i < 2392064) { src = wv; dst = wvb; off = i - 2129920; }
  else                  { src = wp; dst = wpb; off = i - 2392064; }
  float4 v = ((const float4*)src)[off];
  union { unsigned long long u; __bf16 h[4]; } o;
  o.h[0] = (__bf16)v.x; o.h[1] = (__bf16)v.y;
  o.h[2] = (__bf16)v.z; o.h[3] = (__bf16)v.w;
  ((unsigned long long*)dst)[off] = o.u;
}

// ---------------------------------------------------------------------------
// QKV projection GEMM — R4-EXACT (proven ~95us). Per-batch m-tiling: blocks
// never straddle a batch boundary, so every 128B line of q/k/vtb is written
// by ONE block (vtb rows padded to SEQV = whole lines) -> no cross-XCD false
// sharing. (R7/R8's straddling tiles broke this: FETCH +10MB, 95->120us.)
// R3 counted-vmcnt triple-buffer pipeline; chunk swizzle (conflicts 0);
// bijective XCD swizzle (FETCH halved).
// ---------------------------------------------------------------------------
__global__ __launch_bounds__(256) void gemm_qkv(
    const u16* __restrict__ xb,
    const u16* __restrict__ wq, const u16* __restrict__ wk, const u16* __restrict__ wv,
    const float* __restrict__ bq, const float* __restrict__ bk, const float* __restrict__ bv,
    u16* __restrict__ qo, u16* __restrict__ ko, u16* __restrict__ vto) {
  const int bid = blockIdx.x + (blockIdx.y << 3) + blockIdx.z * 416;  // 8*52=416
  const int logical = (bid & 7) * 156 + (bid >> 3);
  const int byz = logical >> 3;
  const int by  = byz % 52;
  const int z   = byz / 52;
  const int bi  = by / 13;               // batch
  const int st  = by % 13;               // s-tile within batch (tile 12: 32 rows)
  const int bn  = (logical & 7) * 128;

  const u16* W = (z == 0) ? wq : (z == 1) ? wk : wv;
  const float* bias = (z == 0) ? bq : (z == 1) ? bk : bv;

  __shared__ __align__(16) u16 sA[3][128 * 32];   // 8KB each
  __shared__ __align__(16) u16 sB[3][128 * 32];   // 8KB each -> 48KB total

  const int tid = threadIdx.x;
  const int wave = tid >> 6;
  const int lane = tid & 63;
  const int l15 = lane & 15;
  const int quad = lane >> 4;
  const int wm = (wave >> 1) * 64;
  const int wn = (wave & 1) * 64;

  // staging: 1KB issue = 16 rows x 4 chunks of 8 u16; source chunk swizzled
  const int sr  = lane >> 2;                                 // 0..15
  const int scs = (((lane & 3) ^ ((lane >> 3) & 3)) << 3);   // swizzled src chunk
  const int r0 = wave * 32;

  // A rows clamped to the batch's last row for the partial tail tile
  int ra1 = st * 128 + r0 + sr;       if (ra1 >= SEQ) ra1 = SEQ - 1;
  int ra2 = st * 128 + r0 + 16 + sr;  if (ra2 >= SEQ) ra2 = SEQ - 1;
  const u16* gA1 = xb + (size_t)(bi * SEQ + ra1) * DIM + scs;
  const u16* gA2 = xb + (size_t)(bi * SEQ + ra2) * DIM + scs;
  const u16* gB1 = W + (size_t)(bn + r0 + sr) * DIM + scs;
  const u16* gB2 = gB1 + 16 * DIM;

  f32x4 acc[4][4] = {};
  const int rsw = (l15 >> 1) & 3;      // read-side swizzle: (row>>1)&3 == (l15>>1)&3

  auto stage = [&](int kk, u16* sAc, u16* sBc) {
    load_lds16(gA1 + kk, sAc + r0 * 32);
    load_lds16(gA2 + kk, sAc + (r0 + 16) * 32);
    load_lds16(gB1 + kk, sBc + r0 * 32);
    load_lds16(gB2 + kk, sBc + (r0 + 16) * 32);
  };

  auto mstep = [&](const u16* sAc, const u16* sBc) {
    bf16x8 a[4], b[4];
#pragma unroll
    for (int mt = 0; mt < 4; mt++)
      a[mt] = *(const bf16x8*)&sAc[(wm + mt * 16 + l15) * 32 + ((quad ^ rsw) << 3)];
#pragma unroll
    for (int nt = 0; nt < 4; nt++)
      b[nt] = *(const bf16x8*)&sBc[(wn + nt * 16 + l15) * 32 + ((quad ^ rsw) << 3)];
#pragma unroll
    for (int mt = 0; mt < 4; mt++)
#pragma unroll
      for (int nt = 0; nt < 4; nt++)
        acc[mt][nt] = __builtin_amdgcn_mfma_f32_16x16x32_bf16(a[mt], b[nt], acc[mt][nt], 0, 0, 0);
  };

  // prologue: 3 K-steps in flight (12 loads/wave outstanding)
  stage(0,  &sA[0][0], &sB[0][0]);
  stage(32, &sA[1][0], &sB[1][0]);
  stage(64, &sA[2][0], &sB[2][0]);

#pragma unroll 1
  for (int t = 0; t < 30; t += 3) {
    WAIT_VM(8); BAR();
    mstep(&sA[0][0], &sB[0][0]);
    LGKM0(); BAR();
    stage((t + 3) * 32, &sA[0][0], &sB[0][0]);

    WAIT_VM(8); BAR();
    mstep(&sA[1][0], &sB[1][0]);
    LGKM0(); BAR();
    stage((t + 4) * 32, &sA[1][0], &sB[1][0]);

    WAIT_VM(8); BAR();
    mstep(&sA[2][0], &sB[2][0]);
    LGKM0(); BAR();
    if (t + 5 < 32) stage((t + 5) * 32, &sA[2][0], &sB[2][0]);
  }
  WAIT_VM(4); BAR();
  mstep(&sA[0][0], &sB[0][0]);
  WAIT_VM(0); BAR();
  mstep(&sA[1][0], &sB[1][0]);

  // epilogue: C/D layout col=lane&15, row=quad*4+reg
#pragma unroll
  for (int nt = 0; nt < 4; nt++) {
    const int n = bn + wn + nt * 16 + l15;
    const float bia = bias[n];
    const int h = n >> 6, d = n & 63;
#pragma unroll
    for (int mt = 0; mt < 4; mt++) {
      const int sbase = st * 128 + wm + mt * 16 + quad * 4;
#pragma unroll
      for (int r = 0; r < 4; r++) {
        const int s = sbase + r;
        if (s < SEQ) {
          float val = acc[mt][nt][r] + bia;
          if (z == 0) val *= QSCALE;
          const __bf16 o = (__bf16)val;
          if (z == 0)
            *(__bf16*)&qo[(((size_t)(bi * NH + h)) * SEQ + s) * HD + d] = o;
          else if (z == 1)
            *(__bf16*)&ko[(((size_t)(bi * NH + h)) * SEQ + s) * HD + d] = o;
          else
            *(__bf16*)&vto[(((size_t)(bi * NH + h)) * HD + d) * SEQV + s] = o;
        }
      }
    }
  }
}

// ---------------------------------------------------------------------------
// Flash attention — R9: 7-wave blocks (448 thr), QBLK = 224 = 7*32 q-rows.
// 1568 = 7*224 exactly -> every q-tile full, no clamps/guards anywhere.
// Each staged K/V tile feeds 224 q-rows (vs 128): staging bytes, barriers,
// and FETCH per q-row x0.57; LDS 48.6KB -> 3 blocks/CU = 21 waves (66% occ).
// Staging: waves 0-3 stage sK, waves 3-6 stage sV (uneven is fine — the
// __syncthreads vmcnt(0) drain covers all waves' loads).
// Kept from R4/R8: swapped QK^T (packed b64 P-stores, lane-local sums),
// per-wave sP, chunk swizzles, setprio around MFMA clusters, bijective XCD
// swizzle (448 = 8*56; 8 heads/XCD).
// ---------------------------------------------------------------------------
__global__ __launch_bounds__(448) void attn(
    const u16* __restrict__ q, const u16* __restrict__ k,
    const u16* __restrict__ vt, u16* __restrict__ ctx) {
  const int bid = blockIdx.x;                     // 0..447
  const int logical = (bid & 7) * 56 + (bid >> 3);
  const int bh = logical / 7;                     // 0..63 (b*16+h)
  const int qt = logical % 7;                     // 0..6, 224 q-rows each
  const int tid = threadIdx.x;
  const int wave = tid >> 6, lane = tid & 63, l15 = lane & 15, quad = lane >> 4;

  __shared__ __align__(16) u16 sK[64 * 64];        // [j][d], chunk-swizzled
  __shared__ __align__(16) u16 sV[64 * 64];        // [d][j], chunk-swizzled
  __shared__ __align__(16) u16 sP[7][32 * PSTR];   // per-wave P [i][j]

  const u16* qh = q + (size_t)bh * (SEQ * HD);
  const u16* kh = k + (size_t)bh * (SEQ * HD);
  const u16* vh = vt + (size_t)bh * (HD * SEQV);

  // Q fragments (MFMA B-operand after the swap); rows always < SEQ (7*224 = 1568)
  bf16x8 aq[2][2];
#pragma unroll
  for (int mt = 0; mt < 2; mt++) {
    const int qrow = qt * 224 + wave * 32 + mt * 16 + l15;
    aq[mt][0] = *(const bf16x8*)&qh[(size_t)qrow * HD + quad * 8];
    aq[mt][1] = *(const bf16x8*)&qh[(size_t)qrow * HD + 32 + quad * 8];
  }

  f32x4 o[2][4] = {};
  float lsum[2] = {0.0f, 0.0f};   // per-lane partial sum over this lane's k subset

  const int jrow = lane >> 3;            // 0..7 row within a 1KB staging issue
  const int cg = (lane & 7) ^ jrow;      // xor-swizzled chunk to fetch
  u16* sPw = sP[wave];
  const int j7 = l15 & 7;

  // ---- 24 full 64-j tiles ----
  for (int j0 = 0; j0 < 1536; j0 += 64) {
    __syncthreads();
    if (wave < 4) {       // sK rows wave*16 .. wave*16+15
      load_lds16(&kh[(size_t)(j0 + wave * 16 + jrow) * HD + cg * 8], &sK[(wave * 16) * 64]);
      load_lds16(&kh[(size_t)(j0 + wave * 16 + 8 + jrow) * HD + cg * 8], &sK[(wave * 16 + 8) * 64]);
    }
    if (wave >= 3) {      // sV rows (wave-3)*16 .. +15 (wave 3 does both)
      const int vw = wave - 3;
      load_lds16(&vh[(size_t)(vw * 16 + jrow) * SEQV + j0 + cg * 8], &sV[(vw * 16) * 64]);
      load_lds16(&vh[(size_t)(vw * 16 + 8 + jrow) * SEQV + j0 + cg * 8], &sV[(vw * 16 + 8) * 64]);
    }
    __syncthreads();

#pragma unroll
    for (int mt = 0; mt < 2; mt++) {
      f32x4 s[4];
      __builtin_amdgcn_s_setprio(1);
#pragma unroll
      for (int jt = 0; jt < 4; jt++) {
        const int j = jt * 16 + l15;
        bf16x8 b0 = *(const bf16x8*)&sK[j * 64 + ((quad ^ j7) * 8)];
        bf16x8 b1 = *(const bf16x8*)&sK[j * 64 + (((4 + quad) ^ j7) * 8)];
        f32x4 acc = {};
        acc = __builtin_amdgcn_mfma_f32_16x16x32_bf16(b0, aq[mt][0], acc, 0, 0, 0);  // swapped
        acc = __builtin_amdgcn_mfma_f32_16x16x32_bf16(b1, aq[mt][1], acc, 0, 0, 0);
        s[jt] = acc;
      }
      __builtin_amdgcn_s_setprio(0);
#pragma unroll
      for (int jt = 0; jt < 4; jt++) {
        bf16x4 pk;
#pragma unroll
        for (int r = 0; r < 4; r++) {
          float p = __builtin_exp2f(s[jt][r]);
          lsum[mt] += p;
          pk[r] = (__bf16)p;
        }
        // row = q (mt*16+l15), cols k = jt*16 + quad*4 .. +3 : one b64 store
        *(bf16x4*)&sPw[(mt * 16 + l15) * PSTR + jt * 16 + quad * 4] = pk;
      }
    }

    LGKM0();

    __builtin_amdgcn_s_setprio(1);
#pragma unroll
    for (int kc = 0; kc < 2; kc++) {
      bf16x8 ap0 = *(const bf16x8*)&sPw[l15 * PSTR + kc * 32 + quad * 8];
      bf16x8 ap1 = *(const bf16x8*)&sPw[(16 + l15) * PSTR + kc * 32 + quad * 8];
#pragma unroll
      for (int dt = 0; dt < 4; dt++) {
        const int d7 = l15 & 7;
        bf16x8 bv = *(const bf16x8*)&sV[(dt * 16 + l15) * 64 + (((kc * 4 + quad) ^ d7) * 8)];
        o[0][dt] = __builtin_amdgcn_mfma_f32_16x16x32_bf16(ap0, bv, o[0][dt], 0, 0, 0);
        o[1][dt] = __builtin_amdgcn_mfma_f32_16x16x32_bf16(ap1, bv, o[1][dt], 0, 0, 0);
      }
    }
    __builtin_amdgcn_s_setprio(0);
  }

  // ---- tail tile: j0 = 1536, 32 valid j (jt 0..1, kc 0) ----
  {
    const int j0 = 1536;
    __syncthreads();
    if (wave < 2) {  // K rows 1536..1567 -> sK rows 0..31 (all in-bounds)
      load_lds16(&kh[(size_t)(j0 + wave * 16 + jrow) * HD + cg * 8], &sK[(wave * 16) * 64]);
      load_lds16(&kh[(size_t)(j0 + wave * 16 + 8 + jrow) * HD + cg * 8], &sK[(wave * 16 + 8) * 64]);
    }
    if (wave >= 3) {  // V cols 1536..1599 always in-plane (SEQV pad)
      const int vw = wave - 3;
      load_lds16(&vh[(size_t)(vw * 16 + jrow) * SEQV + j0 + cg * 8], &sV[(vw * 16) * 64]);
      load_lds16(&vh[(size_t)(vw * 16 + 8 + jrow) * SEQV + j0 + cg * 8], &sV[(vw * 16 + 8) * 64]);
    }
    __syncthreads();

#pragma unroll
    for (int mt = 0; mt < 2; mt++) {
      f32x4 s[2];
#pragma unroll
      for (int jt = 0; jt < 2; jt++) {
        const int j = jt * 16 + l15;
        bf16x8 b0 = *(const bf16x8*)&sK[j * 64 + ((quad ^ j7) * 8)];
        bf16x8 b1 = *(const bf16x8*)&sK[j * 64 + (((4 + quad) ^ j7) * 8)];
        f32x4 acc = {};
        acc = __builtin_amdgcn_mfma_f32_16x16x32_bf16(b0, aq[mt][0], acc, 0, 0, 0);  // swapped
        acc = __builtin_amdgcn_mfma_f32_16x16x32_bf16(b1, aq[mt][1], acc, 0, 0, 0);
        s[jt] = acc;
      }
#pragma unroll
      for (int jt = 0; jt < 2; jt++) {
        bf16x4 pk;
#pragma unroll
        for (int r = 0; r < 4; r++) {
          float p = __builtin_exp2f(s[jt][r]);
          lsum[mt] += p;
          pk[r] = (__bf16)p;
        }
        *(bf16x4*)&sPw[(mt * 16 + l15) * PSTR + jt * 16 + quad * 4] = pk;
      }
    }

    LGKM0();

    {
      bf16x8 ap0 = *(const bf16x8*)&sPw[l15 * PSTR + quad * 8];
      bf16x8 ap1 = *(const bf16x8*)&sPw[(16 + l15) * PSTR + quad * 8];
#pragma unroll
      for (int dt = 0; dt < 4; dt++) {
        const int d7 = l15 & 7;
        bf16x8 bv = *(const bf16x8*)&sV[(dt * 16 + l15) * 64 + ((quad ^ d7) * 8)];
        o[0][dt] = __builtin_amdgcn_mfma_f32_16x16x32_bf16(ap0, bv, o[0][dt], 0, 0, 0);
        o[1][dt] = __builtin_amdgcn_mfma_f32_16x16x32_bf16(ap1, bv, o[1][dt], 0, 0, 0);
      }
    }
  }

  // epilogue: lsum holds this lane's partial over its k subset for q=l15.
  const int bi = bh >> 4, h = bh & 15;
  float Lq[2][4];
#pragma unroll
  for (int mt = 0; mt < 2; mt++) {
    float l = lsum[mt];
    l += __shfl_xor(l, 16);
    l += __shfl_xor(l, 32);          // all lanes: full sum for q = l15 (+mt*16)
#pragma unroll
    for (int r = 0; r < 4; r++)
      Lq[mt][r] = __shfl(l, quad * 4 + r, 16);   // pull q = quad*4+r within 16-group
  }
#pragma unroll
  for (int mt = 0; mt < 2; mt++) {
#pragma unroll
    for (int r = 0; r < 4; r++) {
      const int srow = qt * 224 + wave * 32 + mt * 16 + quad * 4 + r;  // < SEQ always
      const float inv = 1.0f / Lq[mt][r];
#pragma unroll
      for (int dt = 0; dt < 4; dt++)
        *(__bf16*)&ctx[((size_t)(bi * SEQ + srow)) * DIM + h * HD + dt * 16 + l15] =
            (__bf16)(o[mt][dt][r] * inv);
    }
  }
}

// ---------------------------------------------------------------------------
// Output projection — R5 triple-buffer counted-vmcnt pipeline (proven).
// M = 6272 = 49*128 exactly -> no clamps/guards.
// ---------------------------------------------------------------------------
__global__ __launch_bounds__(256) void gemm_out(
    const u16* __restrict__ ctx, const u16* __restrict__ wp,
    const float* __restrict__ bp, float* __restrict__ out) {
  const int bid = blockIdx.x;                    // 0..391
  const int logical = (bid & 7) * 49 + (bid >> 3);
  const int bm = (logical >> 3) * 128;
  const int bn = (logical & 7) * 128;

  __shared__ __align__(16) u16 sA[3][128 * 32];
  __shared__ __align__(16) u16 sB[3][128 * 32];

  const int tid = threadIdx.x;
  const int wave = tid >> 6;
  const int lane = tid & 63;
  const int l15 = lane & 15;
  const int quad = lane >> 4;
  const int wm = (wave >> 1) * 64;
  const int wn = (wave & 1) * 64;
  const int sr  = lane >> 2;
  const int scs = (((lane & 3) ^ ((lane >> 3) & 3)) << 3);
  const int r0 = wave * 32;

  const u16* gA1 = ctx + (size_t)(bm + r0 + sr) * DIM + scs;
  const u16* gA2 = gA1 + 16 * DIM;
  const u16* gB1 = wp + (size_t)(bn + r0 + sr) * DIM + scs;
  const u16* gB2 = gB1 + 16 * DIM;

  f32x4 acc[4][4] = {};
  const int rsw = (l15 >> 1) & 3;

  auto stage = [&](int kk, u16* sAc, u16* sBc) {
    load_lds16(gA1 + kk, sAc + r0 * 32);
    load_lds16(gA2 + kk, sAc + (r0 + 16) * 32);
    load_lds16(gB1 + kk, sBc + r0 * 32);
    load_lds16(gB2 + kk, sBc + (r0 + 16) * 32);
  };

  auto mstep = [&](const u16* sAc, const u16* sBc) {
    bf16x8 a[4], b[4];
#pragma unroll
    for (int mt = 0; mt < 4; mt++)
      a[mt] = *(const bf16x8*)&sAc[(wm + mt * 16 + l15) * 32 + ((quad ^ rsw) << 3)];
#pragma unroll
    for (int nt = 0; nt < 4; nt++)
      b[nt] = *(const bf16x8*)&sBc[(wn + nt * 16 + l15) * 32 + ((quad ^ rsw) << 3)];
#pragma unroll
    for (int mt = 0; mt < 4; mt++)
#pragma unroll
      for (int nt = 0; nt < 4; nt++)
        acc[mt][nt] = __builtin_amdgcn_mfma_f32_16x16x32_bf16(a[mt], b[nt], acc[mt][nt], 0, 0, 0);
  };

  stage(0,  &sA[0][0], &sB[0][0]);
  stage(32, &sA[1][0], &sB[1][0]);
  stage(64, &sA[2][0], &sB[2][0]);

#pragma unroll 1
  for (int t = 0; t < 30; t += 3) {
    WAIT_VM(8); BAR();
    mstep(&sA[0][0], &sB[0][0]);
    LGKM0(); BAR();
    stage((t + 3) * 32, &sA[0][0], &sB[0][0]);

    WAIT_VM(8); BAR();
    mstep(&sA[1][0], &sB[1][0]);
    LGKM0(); BAR();
    stage((t + 4) * 32, &sA[1][0], &sB[1][0]);

    WAIT_VM(8); BAR();
    mstep(&sA[2][0], &sB[2][0]);
    LGKM0(); BAR();
    if (t + 5 < 32) stage((t + 5) * 32, &sA[2][0], &sB[2][0]);
  }
  WAIT_VM(4); BAR();
  mstep(&sA[0][0], &sB[0][0]);
  WAIT_VM(0); BAR();
  mstep(&sA[1][0], &sB[1][0]);

#pragma unroll
  for (int nt = 0; nt < 4; nt++) {
    const int n = bn + wn + nt * 16 + l15;
    const float bia = bp[n];
#pragma unroll
    for (int mt = 0; mt < 4; mt++) {
      const int mbase = bm + wm + mt * 16 + quad * 4;
#pragma unroll
      for (int r = 0; r < 4; r++)
        out[(size_t)(mbase + r) * DIM + n] = acc[mt][nt][r] + bia;
    }
  }
}

// ---------------------------------------------------------------------------
// Workspace layout (bytes):
//  xb   @ 0         : 12,845,056  (x bf16)
//  wqb  @ 12845056  :  2,097,152
//  wkb  @ 14942208  :  2,097,152
//  wvb  @ 17039360  :  2,097,152
//  wpb  @ 19136512  :  2,097,152
//  qb   @ 21233664  : 12,845,056  ([B,H,S,HD] bf16, pre-scaled by QSCALE)
//  kb   @ 34078720  : 12,845,056  ([B,H,S,HD] bf16)
//  vtb  @ 46923776  : 13,107,200  ([B,H,HD,SEQV=1600] bf16, line-aligned rows)
//  ctxb @ 60030976  : 12,845,056  ([B,S,D] bf16)
//  total 72,876,032 bytes
// ---------------------------------------------------------------------------
extern "C" void kernel_launch(void* const* d_in, const int* in_sizes, int n_in,
                              void* d_out, int out_size, void* d_ws, size_t ws_size,
                              hipStream_t stream) {
  const float* x  = (const float*)d_in[0];
  const float* Wq = (const float*)d_in[1];
  const float* bq = (const float*)d_in[2];
  const float* Wk = (const float*)d_in[3];
  const float* bk = (const float*)d_in[4];
  const float* Wv = (const float*)d_in[5];
  const float* bv = (const float*)d_in[6];
  const float* Wp = (const float*)d_in[7];
  const float* bp = (const float*)d_in[8];
  float* out = (float*)d_out;

  char* ws = (char*)d_ws;
  u16* xb   = (u16*)(ws + 0);
  u16* wqb  = (u16*)(ws + 12845056);
  u16* wkb  = (u16*)(ws + 14942208);
  u16* wvb  = (u16*)(ws + 17039360);
  u16* wpb  = (u16*)(ws + 19136512);
  u16* qb   = (u16*)(ws + 21233664);
  u16* kb   = (u16*)(ws + 34078720);
  u16* vtb  = (u16*)(ws + 46923776);
  u16* ctxb = (u16*)(ws + 60030976);

  cvt_all<<<10368, 256, 0, stream>>>(x, Wq, Wk, Wv, Wp, xb, wqb, wkb, wvb, wpb);
  gemm_qkv<<<dim3(8, 52, 3), 256, 0, stream>>>(xb, wqb, wkb, wvb, bq, bk, bv, qb, kb, vtb);
  attn<<<448, 448, 0, stream>>>(qb, kb, vtb, ctxb);
  gemm_out<<<392, 256, 0, stream>>>(ctxb, wpb, bp, out);
}

// Round 10
// 279.249 us; speedup vs baseline: 1.0989x; 1.0989x over previous
//
#include <hip/hip_runtime.h>
#include <stdint.h>

// Problem constants (B,S,D,H fixed by the reference)
#define SEQ 1568
#define SEQV 1600   // vtb padded s-stride: 1600*2B = 25 full 128B lines
#define DIM 1024
#define NB 4
#define NH 16
#define HD 64

typedef unsigned short u16;
typedef __bf16 bf16x8 __attribute__((ext_vector_type(8)));
typedef __bf16 bf16x4 __attribute__((ext_vector_type(4)));
typedef float f32x4 __attribute__((ext_vector_type(4)));

// log2(e)/8: folded into q so QK^T scores come out in exp2 domain
#define QSCALE 0.18033688011112042f

// sP row stride (u16). MUST be >= 64 (P tile is 32 x 64); 72 = 64 + 8 pad
// breaks the power-of-2-stride conflicts. Do not shrink below 64.
#define PSTR 72

// async global->LDS, 16B per lane. LDS dest is wave-uniform base + lane*16.
__device__ __forceinline__ void load_lds16(const u16* g, u16* s) {
  __builtin_amdgcn_global_load_lds((__attribute__((address_space(1))) void*)g,
                                   (__attribute__((address_space(3))) void*)s,
                                   16, 0, 0);
}

#define WAIT_VM(N) asm volatile("s_waitcnt vmcnt(" #N ")" ::: "memory")
#define LGKM0()    asm volatile("s_waitcnt lgkmcnt(0)" ::: "memory")
#define BAR()      do { __builtin_amdgcn_s_barrier(); \
                        __builtin_amdgcn_sched_barrier(0); } while (0)

// ---------------------------------------------------------------------------
// Fused fp32 -> bf16 convert of x + all 4 weights (one launch, 4 elems/thread)
// ---------------------------------------------------------------------------
__global__ __launch_bounds__(256) void cvt_all(
    const float* __restrict__ x,  const float* __restrict__ wq,
    const float* __restrict__ wk, const float* __restrict__ wv,
    const float* __restrict__ wp,
    u16* __restrict__ xb, u16* __restrict__ wqb, u16* __restrict__ wkb,
    u16* __restrict__ wvb, u16* __restrict__ wpb) {
  int i = blockIdx.x * 256 + threadIdx.x;   // grid sized exactly: 2654208 total
  const float* src; u16* dst; int off;
  if (i < 1605632)      { src = x;  dst = xb;  off = i; }
  else if (i < 1867776) { src = wq; dst = wqb; off = i - 1605632; }
  else if (i < 2129920) { src = wk; dst = wkb; off = i - 1867776; }
  else if (i < 2392064) { src = wv; dst = wvb; off = i - 2129920; }
  else                  { src = wp; dst = wpb; off = i - 2392064; }
  float4 v = ((const float4*)src)[off];
  union { unsigned long long u; __bf16 h[4]; } o;
  o.h[0] = (__bf16)v.x; o.h[1] = (__bf16)v.y;
  o.h[2] = (__bf16)v.z; o.h[3] = (__bf16)v.w;
  ((unsigned long long*)dst)[off] = o.u;
}

// ---------------------------------------------------------------------------
// QKV projection GEMM — R4-EXACT (proven ~95us). Per-batch m-tiling: blocks
// never straddle a batch boundary, so every 128B line of q/k/vtb is written
// by ONE block (vtb rows padded to SEQV = whole lines) -> no cross-XCD false
// sharing. (R8's straddling tiles broke this: FETCH +10MB, 95->120us.)
// R3 counted-vmcnt triple-buffer pipeline; chunk swizzle (conflicts 0);
// bijective XCD swizzle (FETCH halved). FROZEN.
// ---------------------------------------------------------------------------
__global__ __launch_bounds__(256) void gemm_qkv(
    const u16* __restrict__ xb,
    const u16* __restrict__ wq, const u16* __restrict__ wk, const u16* __restrict__ wv,
    const float* __restrict__ bq, const float* __restrict__ bk, const float* __restrict__ bv,
    u16* __restrict__ qo, u16* __restrict__ ko, u16* __restrict__ vto) {
  const int bid = blockIdx.x + (blockIdx.y << 3) + blockIdx.z * 416;  // 8*52=416
  const int logical = (bid & 7) * 156 + (bid >> 3);
  const int byz = logical >> 3;
  const int by  = byz % 52;
  const int z   = byz / 52;
  const int bi  = by / 13;               // batch
  const int st  = by % 13;               // s-tile within batch (tile 12: 32 rows)
  const int bn  = (logical & 7) * 128;

  const u16* W = (z == 0) ? wq : (z == 1) ? wk : wv;
  const float* bias = (z == 0) ? bq : (z == 1) ? bk : bv;

  __shared__ __align__(16) u16 sA[3][128 * 32];   // 8KB each
  __shared__ __align__(16) u16 sB[3][128 * 32];   // 8KB each -> 48KB total

  const int tid = threadIdx.x;
  const int wave = tid >> 6;
  const int lane = tid & 63;
  const int l15 = lane & 15;
  const int quad = lane >> 4;
  const int wm = (wave >> 1) * 64;
  const int wn = (wave & 1) * 64;

  // staging: 1KB issue = 16 rows x 4 chunks of 8 u16; source chunk swizzled
  const int sr  = lane >> 2;                                 // 0..15
  const int scs = (((lane & 3) ^ ((lane >> 3) & 3)) << 3);   // swizzled src chunk
  const int r0 = wave * 32;

  // A rows clamped to the batch's last row for the partial tail tile
  int ra1 = st * 128 + r0 + sr;       if (ra1 >= SEQ) ra1 = SEQ - 1;
  int ra2 = st * 128 + r0 + 16 + sr;  if (ra2 >= SEQ) ra2 = SEQ - 1;
  const u16* gA1 = xb + (size_t)(bi * SEQ + ra1) * DIM + scs;
  const u16* gA2 = xb + (size_t)(bi * SEQ + ra2) * DIM + scs;
  const u16* gB1 = W + (size_t)(bn + r0 + sr) * DIM + scs;
  const u16* gB2 = gB1 + 16 * DIM;

  f32x4 acc[4][4] = {};
  const int rsw = (l15 >> 1) & 3;      // read-side swizzle: (row>>1)&3 == (l15>>1)&3

  auto stage = [&](int kk, u16* sAc, u16* sBc) {
    load_lds16(gA1 + kk, sAc + r0 * 32);
    load_lds16(gA2 + kk, sAc + (r0 + 16) * 32);
    load_lds16(gB1 + kk, sBc + r0 * 32);
    load_lds16(gB2 + kk, sBc + (r0 + 16) * 32);
  };

  auto mstep = [&](const u16* sAc, const u16* sBc) {
    bf16x8 a[4], b[4];
#pragma unroll
    for (int mt = 0; mt < 4; mt++)
      a[mt] = *(const bf16x8*)&sAc[(wm + mt * 16 + l15) * 32 + ((quad ^ rsw) << 3)];
#pragma unroll
    for (int nt = 0; nt < 4; nt++)
      b[nt] = *(const bf16x8*)&sBc[(wn + nt * 16 + l15) * 32 + ((quad ^ rsw) << 3)];
#pragma unroll
    for (int mt = 0; mt < 4; mt++)
#pragma unroll
      for (int nt = 0; nt < 4; nt++)
        acc[mt][nt] = __builtin_amdgcn_mfma_f32_16x16x32_bf16(a[mt], b[nt], acc[mt][nt], 0, 0, 0);
  };

  // prologue: 3 K-steps in flight (12 loads/wave outstanding)
  stage(0,  &sA[0][0], &sB[0][0]);
  stage(32, &sA[1][0], &sB[1][0]);
  stage(64, &sA[2][0], &sB[2][0]);

#pragma unroll 1
  for (int t = 0; t < 30; t += 3) {
    WAIT_VM(8); BAR();
    mstep(&sA[0][0], &sB[0][0]);
    LGKM0(); BAR();
    stage((t + 3) * 32, &sA[0][0], &sB[0][0]);

    WAIT_VM(8); BAR();
    mstep(&sA[1][0], &sB[1][0]);
    LGKM0(); BAR();
    stage((t + 4) * 32, &sA[1][0], &sB[1][0]);

    WAIT_VM(8); BAR();
    mstep(&sA[2][0], &sB[2][0]);
    LGKM0(); BAR();
    if (t + 5 < 32) stage((t + 5) * 32, &sA[2][0], &sB[2][0]);
  }
  WAIT_VM(4); BAR();
  mstep(&sA[0][0], &sB[0][0]);
  WAIT_VM(0); BAR();
  mstep(&sA[1][0], &sB[1][0]);

  // epilogue: C/D layout col=lane&15, row=quad*4+reg
#pragma unroll
  for (int nt = 0; nt < 4; nt++) {
    const int n = bn + wn + nt * 16 + l15;
    const float bia = bias[n];
    const int h = n >> 6, d = n & 63;
#pragma unroll
    for (int mt = 0; mt < 4; mt++) {
      const int sbase = st * 128 + wm + mt * 16 + quad * 4;
#pragma unroll
      for (int r = 0; r < 4; r++) {
        const int s = sbase + r;
        if (s < SEQ) {
          float val = acc[mt][nt][r] + bia;
          if (z == 0) val *= QSCALE;
          const __bf16 o = (__bf16)val;
          if (z == 0)
            *(__bf16*)&qo[(((size_t)(bi * NH + h)) * SEQ + s) * HD + d] = o;
          else if (z == 1)
            *(__bf16*)&ko[(((size_t)(bi * NH + h)) * SEQ + s) * HD + d] = o;
          else
            *(__bf16*)&vto[(((size_t)(bi * NH + h)) * HD + d) * SEQV + s] = o;
        }
      }
    }
  }
}

// ---------------------------------------------------------------------------
// Flash attention — R4 geometry RESTORED (256 thr, 832 blocks: R9's 7-wave
// halved blocks/CU -> lost inter-block latency hiding, conflicts 3x).
// R10 change: ONES-MFMA ROW-SUM — one extra MFMA per kc with B = all-ones
// feeds an f32x4 accumulator whose layout (row=quad*4+r) exactly matches
// o[], so the 32 per-tile lsum VALU adds AND the 12-shuffle epilogue
// reduction disappear. Denominator is now summed from the same bf16 P the
// PV numerator uses (rounding partially cancels).
// Kept: swapped QK^T (packed b64 P-stores), chunk swizzles, setprio around
// MFMA clusters, bijective XCD swizzle (FETCH 108->19MB verified).
// ---------------------------------------------------------------------------
__global__ __launch_bounds__(256, 4) void attn(
    const u16* __restrict__ q, const u16* __restrict__ k,
    const u16* __restrict__ vt, u16* __restrict__ ctx) {
  const int bid = blockIdx.x;                     // 0..831
  const int logical = (bid & 7) * 104 + (bid >> 3);
  const int bh = logical / 13;                    // 0..63 (b*16+h)
  const int qt = logical % 13;                    // 0..12, 128 q-rows each
  const int tid = threadIdx.x;
  const int wave = tid >> 6, lane = tid & 63, l15 = lane & 15, quad = lane >> 4;

  __shared__ __align__(16) u16 sK[64 * 64];        // [j][d], chunk-swizzled
  __shared__ __align__(16) u16 sV[64 * 64];        // [d][j], chunk-swizzled
  __shared__ __align__(16) u16 sP[4][32 * PSTR];   // per-wave P [i][j]

  const u16* qh = q + (size_t)bh * (SEQ * HD);
  const u16* kh = k + (size_t)bh * (SEQ * HD);
  const u16* vh = vt + (size_t)bh * (HD * SEQV);

  // Q fragments (MFMA B-operand after the swap; same layout)
  bf16x8 aq[2][2];
#pragma unroll
  for (int mt = 0; mt < 2; mt++) {
    int qrow = qt * 128 + wave * 32 + mt * 16 + l15;
    int qr = qrow < SEQ ? qrow : SEQ - 1;
    aq[mt][0] = *(const bf16x8*)&qh[(size_t)qr * HD + quad * 8];
    aq[mt][1] = *(const bf16x8*)&qh[(size_t)qr * HD + 32 + quad * 8];
  }

  // all-ones B fragment for the row-sum MFMA
  const __bf16 kOne = (__bf16)1.0f;
  const bf16x8 vone = {kOne, kOne, kOne, kOne, kOne, kOne, kOne, kOne};

  f32x4 o[2][4] = {};
  f32x4 ol[2] = {};               // row-sums of P, same layout as o rows

  const int jrow = lane >> 3;            // 0..7 row within a 1KB staging issue
  const int cg = (lane & 7) ^ jrow;      // xor-swizzled chunk to fetch
  u16* sPw = sP[wave];
  const int j7 = l15 & 7;

  // ---- 24 full 64-j tiles ----
  for (int j0 = 0; j0 < 1536; j0 += 64) {
    __syncthreads();
    load_lds16(&kh[(size_t)(j0 + wave * 16 + jrow) * HD + cg * 8], &sK[(wave * 16) * 64]);
    load_lds16(&kh[(size_t)(j0 + wave * 16 + 8 + jrow) * HD + cg * 8], &sK[(wave * 16 + 8) * 64]);
    load_lds16(&vh[(size_t)(wave * 16 + jrow) * SEQV + j0 + cg * 8], &sV[(wave * 16) * 64]);
    load_lds16(&vh[(size_t)(wave * 16 + 8 + jrow) * SEQV + j0 + cg * 8], &sV[(wave * 16 + 8) * 64]);
    __syncthreads();

#pragma unroll
    for (int mt = 0; mt < 2; mt++) {
      f32x4 s[4];
      __builtin_amdgcn_s_setprio(1);
#pragma unroll
      for (int jt = 0; jt < 4; jt++) {
        const int j = jt * 16 + l15;
        bf16x8 b0 = *(const bf16x8*)&sK[j * 64 + ((quad ^ j7) * 8)];
        bf16x8 b1 = *(const bf16x8*)&sK[j * 64 + (((4 + quad) ^ j7) * 8)];
        f32x4 acc = {};
        acc = __builtin_amdgcn_mfma_f32_16x16x32_bf16(b0, aq[mt][0], acc, 0, 0, 0);  // swapped
        acc = __builtin_amdgcn_mfma_f32_16x16x32_bf16(b1, aq[mt][1], acc, 0, 0, 0);
        s[jt] = acc;
      }
      __builtin_amdgcn_s_setprio(0);
#pragma unroll
      for (int jt = 0; jt < 4; jt++) {
        bf16x4 pk;
#pragma unroll
        for (int r = 0; r < 4; r++)
          pk[r] = (__bf16)__builtin_exp2f(s[jt][r]);
        // row = q (mt*16+l15), cols k = jt*16 + quad*4 .. +3 : one b64 store
        *(bf16x4*)&sPw[(mt * 16 + l15) * PSTR + jt * 16 + quad * 4] = pk;
      }
    }

    LGKM0();

    __builtin_amdgcn_s_setprio(1);
#pragma unroll
    for (int kc = 0; kc < 2; kc++) {
      bf16x8 ap0 = *(const bf16x8*)&sPw[l15 * PSTR + kc * 32 + quad * 8];
      bf16x8 ap1 = *(const bf16x8*)&sPw[(16 + l15) * PSTR + kc * 32 + quad * 8];
#pragma unroll
      for (int dt = 0; dt < 4; dt++) {
        const int d7 = l15 & 7;
        bf16x8 bv = *(const bf16x8*)&sV[(dt * 16 + l15) * 64 + (((kc * 4 + quad) ^ d7) * 8)];
        o[0][dt] = __builtin_amdgcn_mfma_f32_16x16x32_bf16(ap0, bv, o[0][dt], 0, 0, 0);
        o[1][dt] = __builtin_amdgcn_mfma_f32_16x16x32_bf16(ap1, bv, o[1][dt], 0, 0, 0);
      }
      ol[0] = __builtin_amdgcn_mfma_f32_16x16x32_bf16(ap0, vone, ol[0], 0, 0, 0);
      ol[1] = __builtin_amdgcn_mfma_f32_16x16x32_bf16(ap1, vone, ol[1], 0, 0, 0);
    }
    __builtin_amdgcn_s_setprio(0);
  }

  // ---- tail tile: j0 = 1536, 32 valid j (jt 0..1, kc 0) ----
  {
    const int j0 = 1536;
    __syncthreads();
    if (wave < 2) {  // K rows 1536..1567 -> sK rows 0..31
      load_lds16(&kh[(size_t)(j0 + wave * 16 + jrow) * HD + cg * 8], &sK[(wave * 16) * 64]);
      load_lds16(&kh[(size_t)(j0 + wave * 16 + 8 + jrow) * HD + cg * 8], &sK[(wave * 16 + 8) * 64]);
    }
    // V cols 1536..1599 always in-plane (SEQV pad); pad chunks 4..7 unread
    load_lds16(&vh[(size_t)(wave * 16 + jrow) * SEQV + j0 + cg * 8], &sV[(wave * 16) * 64]);
    load_lds16(&vh[(size_t)(wave * 16 + 8 + jrow) * SEQV + j0 + cg * 8], &sV[(wave * 16 + 8) * 64]);
    __syncthreads();

#pragma unroll
    for (int mt = 0; mt < 2; mt++) {
      f32x4 s[2];
#pragma unroll
      for (int jt = 0; jt < 2; jt++) {
        const int j = jt * 16 + l15;
        bf16x8 b0 = *(const bf16x8*)&sK[j * 64 + ((quad ^ j7) * 8)];
        bf16x8 b1 = *(const bf16x8*)&sK[j * 64 + (((4 + quad) ^ j7) * 8)];
        f32x4 acc = {};
        acc = __builtin_amdgcn_mfma_f32_16x16x32_bf16(b0, aq[mt][0], acc, 0, 0, 0);  // swapped
        acc = __builtin_amdgcn_mfma_f32_16x16x32_bf16(b1, aq[mt][1], acc, 0, 0, 0);
        s[jt] = acc;
      }
#pragma unroll
      for (int jt = 0; jt < 2; jt++) {
        bf16x4 pk;
#pragma unroll
        for (int r = 0; r < 4; r++)
          pk[r] = (__bf16)__builtin_exp2f(s[jt][r]);
        *(bf16x4*)&sPw[(mt * 16 + l15) * PSTR + jt * 16 + quad * 4] = pk;
      }
    }

    LGKM0();

    {
      bf16x8 ap0 = *(const bf16x8*)&sPw[l15 * PSTR + quad * 8];
      bf16x8 ap1 = *(const bf16x8*)&sPw[(16 + l15) * PSTR + quad * 8];
#pragma unroll
      for (int dt = 0; dt < 4; dt++) {
        const int d7 = l15 & 7;
        bf16x8 bv = *(const bf16x8*)&sV[(dt * 16 + l15) * 64 + ((quad ^ d7) * 8)];
        o[0][dt] = __builtin_amdgcn_mfma_f32_16x16x32_bf16(ap0, bv, o[0][dt], 0, 0, 0);
        o[1][dt] = __builtin_amdgcn_mfma_f32_16x16x32_bf16(ap1, bv, o[1][dt], 0, 0, 0);
      }
      ol[0] = __builtin_amdgcn_mfma_f32_16x16x32_bf16(ap0, vone, ol[0], 0, 0, 0);
      ol[1] = __builtin_amdgcn_mfma_f32_16x16x32_bf16(ap1, vone, ol[1], 0, 0, 0);
    }
  }

  // epilogue: ol[mt][r] = full row-sum for q-row = mt*16 + quad*4 + r
  // (every l15 column holds the same value) — no cross-lane reduction needed.
  const int bi = bh >> 4, h = bh & 15;
#pragma unroll
  for (int mt = 0; mt < 2; mt++) {
#pragma unroll
    for (int r = 0; r < 4; r++) {
      const int srow = qt * 128 + wave * 32 + mt * 16 + quad * 4 + r;
      if (srow < SEQ) {
        const float inv = 1.0f / ol[mt][r];
#pragma unroll
        for (int dt = 0; dt < 4; dt++)
          *(__bf16*)&ctx[((size_t)(bi * SEQ + srow)) * DIM + h * HD + dt * 16 + l15] =
              (__bf16)(o[mt][dt][r] * inv);
      }
    }
  }
}

// ---------------------------------------------------------------------------
// Output projection — R5 triple-buffer counted-vmcnt pipeline (proven).
// M = 6272 = 49*128 exactly -> no clamps/guards.
// ---------------------------------------------------------------------------
__global__ __launch_bounds__(256) void gemm_out(
    const u16* __restrict__ ctx, const u16* __restrict__ wp,
    const float* __restrict__ bp, float* __restrict__ out) {
  const int bid = blockIdx.x;                    // 0..391
  const int logical = (bid & 7) * 49 + (bid >> 3);
  const int bm = (logical >> 3) * 128;
  const int bn = (logical & 7) * 128;

  __shared__ __align__(16) u16 sA[3][128 * 32];
  __shared__ __align__(16) u16 sB[3][128 * 32];

  const int tid = threadIdx.x;
  const int wave = tid >> 6;
  const int lane = tid & 63;
  const int l15 = lane & 15;
  const int quad = lane >> 4;
  const int wm = (wave >> 1) * 64;
  const int wn = (wave & 1) * 64;
  const int sr  = lane >> 2;
  const int scs = (((lane & 3) ^ ((lane >> 3) & 3)) << 3);
  const int r0 = wave * 32;

  const u16* gA1 = ctx + (size_t)(bm + r0 + sr) * DIM + scs;
  const u16* gA2 = gA1 + 16 * DIM;
  const u16* gB1 = wp + (size_t)(bn + r0 + sr) * DIM + scs;
  const u16* gB2 = gB1 + 16 * DIM;

  f32x4 acc[4][4] = {};
  const int rsw = (l15 >> 1) & 3;

  auto stage = [&](int kk, u16* sAc, u16* sBc) {
    load_lds16(gA1 + kk, sAc + r0 * 32);
    load_lds16(gA2 + kk, sAc + (r0 + 16) * 32);
    load_lds16(gB1 + kk, sBc + r0 * 32);
    load_lds16(gB2 + kk, sBc + (r0 + 16) * 32);
  };

  auto mstep = [&](const u16* sAc, const u16* sBc) {
    bf16x8 a[4], b[4];
#pragma unroll
    for (int mt = 0; mt < 4; mt++)
      a[mt] = *(const bf16x8*)&sAc[(wm + mt * 16 + l15) * 32 + ((quad ^ rsw) << 3)];
#pragma unroll
    for (int nt = 0; nt < 4; nt++)
      b[nt] = *(const bf16x8*)&sBc[(wn + nt * 16 + l15) * 32 + ((quad ^ rsw) << 3)];
#pragma unroll
    for (int mt = 0; mt < 4; mt++)
#pragma unroll
      for (int nt = 0; nt < 4; nt++)
        acc[mt][nt] = __builtin_amdgcn_mfma_f32_16x16x32_bf16(a[mt], b[nt], acc[mt][nt], 0, 0, 0);
  };

  stage(0,  &sA[0][0], &sB[0][0]);
  stage(32, &sA[1][0], &sB[1][0]);
  stage(64, &sA[2][0], &sB[2][0]);

#pragma unroll 1
  for (int t = 0; t < 30; t += 3) {
    WAIT_VM(8); BAR();
    mstep(&sA[0][0], &sB[0][0]);
    LGKM0(); BAR();
    stage((t + 3) * 32, &sA[0][0], &sB[0][0]);

    WAIT_VM(8); BAR();
    mstep(&sA[1][0], &sB[1][0]);
    LGKM0(); BAR();
    stage((t + 4) * 32, &sA[1][0], &sB[1][0]);

    WAIT_VM(8); BAR();
    mstep(&sA[2][0], &sB[2][0]);
    LGKM0(); BAR();
    if (t + 5 < 32) stage((t + 5) * 32, &sA[2][0], &sB[2][0]);
  }
  WAIT_VM(4); BAR();
  mstep(&sA[0][0], &sB[0][0]);
  WAIT_VM(0); BAR();
  mstep(&sA[1][0], &sB[1][0]);

#pragma unroll
  for (int nt = 0; nt < 4; nt++) {
    const int n = bn + wn + nt * 16 + l15;
    const float bia = bp[n];
#pragma unroll
    for (int mt = 0; mt < 4; mt++) {
      const int mbase = bm + wm + mt * 16 + quad * 4;
#pragma unroll
      for (int r = 0; r < 4; r++)
        out[(size_t)(mbase + r) * DIM + n] = acc[mt][nt][r] + bia;
    }
  }
}

// ---------------------------------------------------------------------------
// Workspace layout (bytes):
//  xb   @ 0         : 12,845,056  (x bf16)
//  wqb  @ 12845056  :  2,097,152
//  wkb  @ 14942208  :  2,097,152
//  wvb  @ 17039360  :  2,097,152
//  wpb  @ 19136512  :  2,097,152
//  qb   @ 21233664  : 12,845,056  ([B,H,S,HD] bf16, pre-scaled by QSCALE)
//  kb   @ 34078720  : 12,845,056  ([B,H,S,HD] bf16)
//  vtb  @ 46923776  : 13,107,200  ([B,H,HD,SEQV=1600] bf16, line-aligned rows)
//  ctxb @ 60030976  : 12,845,056  ([B,S,D] bf16)
//  total 72,876,032 bytes
// ---------------------------------------------------------------------------
extern "C" void kernel_launch(void* const* d_in, const int* in_sizes, int n_in,
                              void* d_out, int out_size, void* d_ws, size_t ws_size,
                              hipStream_t stream) {
  const float* x  = (const float*)d_in[0];
  const float* Wq = (const float*)d_in[1];
  const float* bq = (const float*)d_in[2];
  const float* Wk = (const float*)d_in[3];
  const float* bk = (const float*)d_in[4];
  const float* Wv = (const float*)d_in[5];
  const float* bv = (const float*)d_in[6];
  const float* Wp = (const float*)d_in[7];
  const float* bp = (const float*)d_in[8];
  float* out = (float*)d_out;

  char* ws = (char*)d_ws;
  u16* xb   = (u16*)(ws + 0);
  u16* wqb  = (u16*)(ws + 12845056);
  u16* wkb  = (u16*)(ws + 14942208);
  u16* wvb  = (u16*)(ws + 17039360);
  u16* wpb  = (u16*)(ws + 19136512);
  u16* qb   = (u16*)(ws + 21233664);
  u16* kb   = (u16*)(ws + 34078720);
  u16* vtb  = (u16*)(ws + 46923776);
  u16* ctxb = (u16*)(ws + 60030976);

  cvt_all<<<10368, 256, 0, stream>>>(x, Wq, Wk, Wv, Wp, xb, wqb, wkb, wvb, wpb);
  gemm_qkv<<<dim3(8, 52, 3), 256, 0, stream>>>(xb, wqb, wkb, wvb, bq, bk, bv, qb, kb, vtb);
  attn<<<832, 256, 0, stream>>>(qb, kb, vtb, ctxb);
  gemm_out<<<392, 256, 0, stream>>>(ctxb, wpb, bp, out);
}